// Round 1
// baseline (2823.460 us; speedup 1.0000x reference)
//
#include <hip/hip_runtime.h>
#include <hip/hip_bf16.h>

typedef __hip_bfloat16 bf16;

#define NQ 128
#define HD 512
#define FD 256
#define NC 6
#define IMH 48
#define IMW 120
#define HW 5760   // 48*120

// ---------------------------------------------------------------------------
// Transpose features (NC, FD, HW) f32  ->  (NC, HW, FD) bf16
// ---------------------------------------------------------------------------
__global__ __launch_bounds__(256) void transpose_feat_k(const float* __restrict__ f,
                                                        bf16* __restrict__ ft)
{
    __shared__ float tile[32][33];
    int cam = blockIdx.z;
    int hw0 = blockIdx.x * 32, fd0 = blockIdx.y * 32;
    int tx = threadIdx.x, ty = threadIdx.y;
    const float* fb = f + (size_t)cam * FD * HW;
    for (int r = ty; r < 32; r += 8)
        tile[r][tx] = fb[(size_t)(fd0 + r) * HW + hw0 + tx];
    __syncthreads();
    bf16* fo = ft + (size_t)cam * HW * FD;
    for (int r = ty; r < 32; r += 8)
        fo[(size_t)(hw0 + r) * FD + fd0 + tx] = __float2bfloat16(tile[tx][r]);
}

// ---------------------------------------------------------------------------
// Generic GEMM: C[m][n] = act( sum_k A[m][k]*W[n][k] + bias[n] ) (+ R[m][n])
// M=128 fixed, tiles 32x32, 256 threads, each thread 4 rows x 1 col.
// LDS stores A and W transposed ([k][m] / [k][n], pad 36) so the inner loop is
// one ds_read_b128 (4 A vals) + one ds_read_b32 (W) per 4 FMAs.
// ---------------------------------------------------------------------------
__device__ __forceinline__ void gemm_body(const float* __restrict__ A, int lda,
                                          const float* __restrict__ W, int ldw,
                                          const float* __restrict__ bias,
                                          const float* __restrict__ R, int ldr,
                                          float* __restrict__ C, int ldc,
                                          int K, int act, int m0, int n0)
{
    __shared__ float Ast[32 * 36];
    __shared__ float Wst[32 * 36];
    int tid = threadIdx.x;
    int col = tid & 31;
    int rg  = (tid >> 5) * 4;          // base row (0,4,...,28)
    int arow = tid >> 3;               // 0..31
    int ac4  = (tid & 7) << 2;         // 0,4,...,28
    const float* Ald = A + (size_t)(m0 + arow) * lda + ac4;
    const float* Wld = W + (size_t)(n0 + arow) * ldw + ac4;
    float acc[4] = {0.f, 0.f, 0.f, 0.f};

    for (int k0 = 0; k0 < K; k0 += 32) {
        float4 av = *(const float4*)(Ald + k0);
        float4 wv = *(const float4*)(Wld + k0);
        Ast[(ac4 + 0) * 36 + arow] = av.x;
        Ast[(ac4 + 1) * 36 + arow] = av.y;
        Ast[(ac4 + 2) * 36 + arow] = av.z;
        Ast[(ac4 + 3) * 36 + arow] = av.w;
        Wst[(ac4 + 0) * 36 + arow] = wv.x;
        Wst[(ac4 + 1) * 36 + arow] = wv.y;
        Wst[(ac4 + 2) * 36 + arow] = wv.z;
        Wst[(ac4 + 3) * 36 + arow] = wv.w;
        __syncthreads();
#pragma unroll
        for (int k = 0; k < 32; k++) {
            float4 a = *(const float4*)&Ast[k * 36 + rg];
            float  w = Wst[k * 36 + col];
            acc[0] += a.x * w; acc[1] += a.y * w;
            acc[2] += a.z * w; acc[3] += a.w * w;
        }
        __syncthreads();
    }

    float bv = bias[n0 + col];
#pragma unroll
    for (int jj = 0; jj < 4; jj++) {
        int m = m0 + rg + jj;
        float v = acc[jj] + bv;
        if (act == 1) v = fmaxf(v, 0.0f);
        if (R) v += R[(size_t)m * ldr + n0 + col];
        C[(size_t)m * ldc + n0 + col] = v;
    }
}

__global__ __launch_bounds__(256) void gemm_k(const float* __restrict__ A, int lda,
                                              const float* __restrict__ W, int ldw,
                                              const float* __restrict__ bias,
                                              const float* __restrict__ R, int ldr,
                                              float* __restrict__ C, int ldc,
                                              int K, int act)
{
    gemm_body(A, lda, W, ldw, bias, R, ldr, C, ldc, K, act,
              blockIdx.y * 32, blockIdx.x * 32);
}

// fused hidden GEMM for the three prediction heads (motion/type/attr), relu
__global__ __launch_bounds__(256) void gemm3_k(const float* __restrict__ A,
                                               const float* __restrict__ W0, const float* __restrict__ B0,
                                               const float* __restrict__ W1, const float* __restrict__ B1,
                                               const float* __restrict__ W2, const float* __restrict__ B2,
                                               float* __restrict__ C)
{
    int widx = blockIdx.x >> 4;
    const float* W  = (widx == 0) ? W0 : (widx == 1 ? W1 : W2);
    const float* Bv = (widx == 0) ? B0 : (widx == 1 ? B1 : B2);
    gemm_body(A, 512, W, 512, Bv, nullptr, 0, C + widx * 65536, 512, 512, 1,
              blockIdx.y * 32, (blockIdx.x & 15) * 32);
}

// ---------------------------------------------------------------------------
// Head output: out[q][n] = act( hid_row . w2_row + b ), written into d_out
// grid (128, 24), block 64 (one wave): n<11 motion (sigmoid-affine),
// n<21 type (linear), else attr (sigmoid)
// ---------------------------------------------------------------------------
__global__ __launch_bounds__(64) void heads2_k(const float* __restrict__ hid,
                                               const float* __restrict__ w2m, const float* __restrict__ b2m,
                                               const float* __restrict__ w2t, const float* __restrict__ b2t,
                                               const float* __restrict__ w2a, const float* __restrict__ b2a,
                                               const float* __restrict__ pmin, const float* __restrict__ pmax,
                                               float* __restrict__ out)
{
    int q = blockIdx.x, n = blockIdx.y, lane = threadIdx.x;
    const float* Hp; const float* wr; float bv; int mode;
    if (n < 11)      { Hp = hid;           wr = w2m + n * 512;        bv = b2m[n];      mode = 0; }
    else if (n < 21) { Hp = hid + 65536;   wr = w2t + (n - 11) * 512; bv = b2t[n - 11]; mode = 1; }
    else             { Hp = hid + 131072;  wr = w2a + (n - 21) * 512; bv = b2a[n - 21]; mode = 2; }
    const float4* h4 = (const float4*)(Hp + q * 512);
    const float4* w4 = (const float4*)wr;
    float4 a0 = h4[lane],      c0 = w4[lane];
    float4 a1 = h4[lane + 64], c1 = w4[lane + 64];
    float acc = a0.x * c0.x + a0.y * c0.y + a0.z * c0.z + a0.w * c0.w
              + a1.x * c1.x + a1.y * c1.y + a1.z * c1.z + a1.w * c1.w;
    for (int off = 32; off; off >>= 1) acc += __shfl_xor(acc, off);
    if (lane == 0) {
        float v = acc + bv;
        if (mode == 0)      v = (1.0f / (1.0f + __expf(-v))) * (pmax[n] - pmin[n]) + pmin[n];
        else if (mode == 2) v = 1.0f / (1.0f + __expf(-v));
        out[q * 24 + n] = v;
    }
}

// ---------------------------------------------------------------------------
// LayerNorm over 512 dims, one block per row (in-place safe)
// ---------------------------------------------------------------------------
__global__ __launch_bounds__(256) void ln_k(const float* __restrict__ in,
                                            const float* __restrict__ g,
                                            const float* __restrict__ b,
                                            float* __restrict__ out)
{
    int row = blockIdx.x, tid = threadIdx.x;
    float v0 = in[row * 512 + tid];
    float v1 = in[row * 512 + tid + 256];
    float s = v0 + v1, s2 = v0 * v0 + v1 * v1;
    for (int off = 32; off; off >>= 1) { s += __shfl_xor(s, off); s2 += __shfl_xor(s2, off); }
    __shared__ float sh[8];
    if ((tid & 63) == 0) { sh[tid >> 6] = s; sh[4 + (tid >> 6)] = s2; }
    __syncthreads();
    s  = sh[0] + sh[1] + sh[2] + sh[3];
    s2 = sh[4] + sh[5] + sh[6] + sh[7];
    float mean = s * (1.0f / 512.0f);
    float var  = s2 * (1.0f / 512.0f) - mean * mean;
    float rs = rsqrtf(var + 1e-5f);
    out[row * 512 + tid]       = (v0 - mean) * rs * g[tid] + b[tid];
    out[row * 512 + tid + 256] = (v1 - mean) * rs * g[tid + 256] + b[tid + 256];
}

// ---------------------------------------------------------------------------
// MHA core on a packed qkv buffer (128 x 1536 = [Q|K|V], heads of 64 dims).
// grid = 8 heads * 4 row-chunks of 32 query rows; block 256 (4 waves).
// Wave w handles rows w*8..w*8+7; lane j computes scores j and j+64.
// ---------------------------------------------------------------------------
__global__ __launch_bounds__(256) void attn_k(const float* __restrict__ qkv,
                                              float* __restrict__ out)
{
    __shared__ float KVl[128 * 68];   // K[128][68]; later reused as Vt[64][132]
    __shared__ float Ql[32 * 68];
    __shared__ float Pl[32 * 128];
    int h = blockIdx.x >> 2, chunk = blockIdx.x & 3;
    int tid = threadIdx.x;

    for (int l = tid; l < 2048; l += 256) {            // K: 128 rows x 16 float4
        int row = l >> 4, c4 = (l & 15) * 4;
        float4 v = *(const float4*)&qkv[row * 1536 + 512 + h * 64 + c4];
        *(float4*)&KVl[row * 68 + c4] = v;
    }
    for (int l = tid; l < 512; l += 256) {             // Q: 32 rows x 16 float4
        int row = l >> 4, c4 = (l & 15) * 4;
        float4 v = *(const float4*)&qkv[(chunk * 32 + row) * 1536 + h * 64 + c4];
        *(float4*)&Ql[row * 68 + c4] = v;
    }
    __syncthreads();

    int w = tid >> 6, j = tid & 63;
    for (int r8 = 0; r8 < 8; r8++) {
        int lr = w * 8 + r8;
        float s0 = 0.f, s1 = 0.f;
#pragma unroll
        for (int k4 = 0; k4 < 64; k4 += 4) {
            float4 qv  = *(const float4*)&Ql[lr * 68 + k4];
            float4 k0v = *(const float4*)&KVl[j * 68 + k4];
            float4 k1v = *(const float4*)&KVl[(j + 64) * 68 + k4];
            s0 += qv.x * k0v.x + qv.y * k0v.y + qv.z * k0v.z + qv.w * k0v.w;
            s1 += qv.x * k1v.x + qv.y * k1v.y + qv.z * k1v.z + qv.w * k1v.w;
        }
        s0 *= 0.125f; s1 *= 0.125f;
        float m = fmaxf(s0, s1);
        for (int off = 32; off; off >>= 1) m = fmaxf(m, __shfl_xor(m, off));
        float e0 = __expf(s0 - m), e1 = __expf(s1 - m);
        float sm = e0 + e1;
        for (int off = 32; off; off >>= 1) sm += __shfl_xor(sm, off);
        float inv = 1.0f / sm;
        Pl[lr * 128 + j]      = e0 * inv;
        Pl[lr * 128 + j + 64] = e1 * inv;
    }
    __syncthreads();

    for (int l = tid; l < 2048; l += 256) {            // V transposed: Vt[d][row]
        int row = l >> 4, c4 = (l & 15) * 4;
        float4 v = *(const float4*)&qkv[row * 1536 + 1024 + h * 64 + c4];
        KVl[(c4 + 0) * 132 + row] = v.x;
        KVl[(c4 + 1) * 132 + row] = v.y;
        KVl[(c4 + 2) * 132 + row] = v.z;
        KVl[(c4 + 3) * 132 + row] = v.w;
    }
    __syncthreads();

    int d = tid & 63, w2 = tid >> 6;
    for (int r8 = 0; r8 < 8; r8++) {
        int lr = w2 * 8 + r8;
        float o = 0.f;
#pragma unroll
        for (int j4 = 0; j4 < 128; j4 += 4) {
            float4 pv = *(const float4*)&Pl[lr * 128 + j4];
            float4 vv = *(const float4*)&KVl[d * 132 + j4];
            o += pv.x * vv.x + pv.y * vv.y + pv.z * vv.z + pv.w * vv.w;
        }
        out[(chunk * 32 + lr) * 512 + h * 64 + d] = o;
    }
}

// ---------------------------------------------------------------------------
// Box-point sampling + 6-camera projection + bilinear gather + aggregate.
// grid (128 queries, 2 channel-halves), block 256.
// Phase 1: 576 (cam,point) projections -> 2304 (offset, weight) taps in LDS.
// Phase 2: 128 channels x 2 tap-halves, block-uniform zero-weight skip.
// ---------------------------------------------------------------------------
__global__ __launch_bounds__(256) void gather_k(const bf16* __restrict__ ft,
                                                const float* __restrict__ proj,
                                                const float* __restrict__ preds,
                                                float* __restrict__ agg)
{
    __shared__ float mo[11];
    __shared__ int   goff[2304];
    __shared__ float gw[2304];
    __shared__ float part[128];
    int n = blockIdx.x, half = blockIdx.y, tid = threadIdx.x;
    if (tid < 11) mo[tid] = preds[n * 24 + tid];
    __syncthreads();
    float dd0 = mo[8], dd1 = mo[9], dd2 = mo[10];
    float c0 = mo[0], c1 = mo[1], c2 = mo[2];
    float sy, cy;
    sincosf(mo[7], &sy, &cy);

    for (int l = tid; l < 576; l += 256) {
        int cam = l / 96, p = l - cam * 96;
        int face = p >> 4, axis = face >> 1;
        float sgn = (face & 1) ? 0.5f : -0.5f;
        float offi = -0.4f + (float)((p >> 2) & 3) * (0.8f / 3.0f);
        float offj = -0.4f + (float)(p & 3) * (0.8f / 3.0f);
        float t0, t1, t2;
        if (axis == 0)      { t0 = sgn;  t1 = offi; t2 = offj; }
        else if (axis == 1) { t0 = offi; t1 = sgn;  t2 = offj; }
        else                { t0 = offi; t1 = offj; t2 = sgn;  }
        float px = t0 * dd0, py = t1 * dd1, pz = t2 * dd2;
        float X = px * cy - py * sy + c0;
        float Y = px * sy + py * cy + c1;
        float Z = pz + c2;
        const float* P = proj + cam * 12;
        float cu = P[0] * X + P[1] * Y + P[2] * Z + P[3];
        float cv = P[4] * X + P[5] * Y + P[6] * Z + P[7];
        float cz = P[8] * X + P[9] * Y + P[10] * Z + P[11];
        float zs = (fabsf(cz) > 1e-6f) ? cz : 1e-6f;
        float u = cu / zs, v = cv / zs;
        bool front = cz > 0.0f;
        float u0 = floorf(u), v0 = floorf(v);
        float du = u - u0, dv = v - v0;
        float us[4] = {u0, u0 + 1.0f, u0, u0 + 1.0f};
        float vs[4] = {v0, v0, v0 + 1.0f, v0 + 1.0f};
        float wt[4] = {(1.0f - du) * (1.0f - dv), du * (1.0f - dv),
                       (1.0f - du) * dv, du * dv};
#pragma unroll
        for (int t = 0; t < 4; t++) {
            bool ok = front && (us[t] >= 0.0f) && (us[t] <= 119.0f)
                            && (vs[t] >= 0.0f) && (vs[t] <= 47.0f);
            float ucl = fminf(fmaxf(us[t], 0.0f), 119.0f);
            float vcl = fminf(fmaxf(vs[t], 0.0f), 47.0f);
            int idx = (int)vcl * IMW + (int)ucl;
            goff[l * 4 + t] = cam * (HW * FD) + idx * FD;
            gw[l * 4 + t]   = ok ? wt[t] : 0.0f;
        }
    }
    __syncthreads();

    int cl = tid & 127, prt = tid >> 7;
    const bf16* ftc = ft + half * 128 + cl;
    float acc = 0.0f;
    int e0 = prt * 1152;
    for (int e = e0; e < e0 + 1152; e++) {
        float wv = gw[e];
        if (wv != 0.0f) acc += wv * __bfloat162float(ftc[goff[e]]);
    }
    if (prt == 0) part[cl] = acc;
    __syncthreads();
    if (prt == 1) agg[n * 256 + half * 128 + cl] = (acc + part[cl]) * (1.0f / 576.0f);
}

// ---------------------------------------------------------------------------
extern "C" void kernel_launch(void* const* d_in, const int* in_sizes, int n_in,
                              void* d_out, int out_size, void* d_ws, size_t ws_size,
                              hipStream_t stream)
{
    const float* features  = (const float*)d_in[0];
    const float* proj      = (const float*)d_in[1];
    const float* queries0  = (const float*)d_in[3];
    const float* pmin      = (const float*)d_in[4];
    const float* pmax      = (const float*)d_in[5];
    const float* motion_w1 = (const float*)d_in[6];
    const float* motion_b1 = (const float*)d_in[7];
    const float* motion_w2 = (const float*)d_in[8];
    const float* motion_b2 = (const float*)d_in[9];
    const float* type_w1   = (const float*)d_in[10];
    const float* type_b1   = (const float*)d_in[11];
    const float* type_w2   = (const float*)d_in[12];
    const float* type_b2   = (const float*)d_in[13];
    const float* attr_w1   = (const float*)d_in[14];
    const float* attr_b1   = (const float*)d_in[15];
    const float* attr_w2   = (const float*)d_in[16];
    const float* attr_b2   = (const float*)d_in[17];
    const float* fmlp_w1   = (const float*)d_in[18];
    const float* fmlp_b1   = (const float*)d_in[19];
    const float* fmlp_w2   = (const float*)d_in[20];
    const float* fmlp_b2   = (const float*)d_in[21];
    const float* sa_in_w   = (const float*)d_in[22];
    const float* sa_in_b   = (const float*)d_in[23];
    const float* sa_out_w  = (const float*)d_in[24];
    const float* sa_out_b  = (const float*)d_in[25];
    const float* fa_in_w   = (const float*)d_in[26];
    const float* fa_in_b   = (const float*)d_in[27];
    const float* fa_out_w  = (const float*)d_in[28];
    const float* fa_out_b  = (const float*)d_in[29];
    const float* ffn_w1    = (const float*)d_in[30];
    const float* ffn_b1    = (const float*)d_in[31];
    const float* ffn_w2    = (const float*)d_in[32];
    const float* ffn_b2    = (const float*)d_in[33];
    const float* ln1_g     = (const float*)d_in[34];
    const float* ln1_b     = (const float*)d_in[35];
    const float* ln2_g     = (const float*)d_in[36];
    const float* ln2_b     = (const float*)d_in[37];
    const float* ln3_g     = (const float*)d_in[38];
    const float* ln3_b     = (const float*)d_in[39];
    float* out = (float*)d_out;

    // workspace layout
    char* wsb = (char*)d_ws;
    bf16* feat_t = (bf16*)wsb;                       // 6*5760*256 bf16 = 17,694,720 B
    float* fbase = (float*)(wsb + (size_t)NC * HW * FD * sizeof(bf16));
    float* q      = fbase;                 // 128*512
    float* x      = q + 65536;             // 128*512
    float* qkv    = x + 65536;             // 128*1536
    float* attn   = qkv + 196608;          // 128*512
    float* hid    = attn + 65536;          // 128*2048 (also 3 head-hidden slabs)
    float* agg    = hid + 262144;          // 128*256
    float* feat_h = agg + 32768;           // 128*512

    transpose_feat_k<<<dim3(180, 8, 6), dim3(32, 8), 0, stream>>>(features, feat_t);
    hipMemcpyAsync(q, queries0, 65536 * sizeof(float), hipMemcpyDeviceToDevice, stream);

    for (int i = 0; i < 6; i++) {
        // prediction heads (read q as-is)
        gemm3_k<<<dim3(48, 4), 256, 0, stream>>>(q, motion_w1, motion_b1,
                                                 type_w1, type_b1, attr_w1, attr_b1, hid);
        heads2_k<<<dim3(128, 24), 64, 0, stream>>>(hid, motion_w2, motion_b2,
                                                   type_w2, type_b2, attr_w2, attr_b2,
                                                   pmin, pmax, out + i * 3072);
        if (i == 5) break;

        // deformable-style feature gather (reads motion params from d_out)
        gather_k<<<dim3(128, 2), 256, 0, stream>>>(feat_t, proj, out + i * 3072, agg);
        gemm_k<<<dim3(16, 4), 256, 0, stream>>>(agg, 256, fmlp_w1, 256, fmlp_b1,
                                                nullptr, 0, hid, 512, 256, 1);
        gemm_k<<<dim3(16, 4), 256, 0, stream>>>(hid, 512, fmlp_w2, 512, fmlp_b2,
                                                nullptr, 0, feat_h, 512, 512, 0);

        // self-attention
        ln_k<<<128, 256, 0, stream>>>(q, ln1_g + i * 512, ln1_b + i * 512, x);
        gemm_k<<<dim3(48, 4), 256, 0, stream>>>(x, 512, sa_in_w + (size_t)i * 786432, 512,
                                                sa_in_b + i * 1536, nullptr, 0, qkv, 1536, 512, 0);
        attn_k<<<32, 256, 0, stream>>>(qkv, attn);
        gemm_k<<<dim3(16, 4), 256, 0, stream>>>(attn, 512, sa_out_w + (size_t)i * 262144, 512,
                                                sa_out_b + i * 512, x, 512, x, 512, 512, 0);

        // cross-attention (Q from x, K/V from feat_h)
        ln_k<<<128, 256, 0, stream>>>(x, ln2_g + i * 512, ln2_b + i * 512, x);
        gemm_k<<<dim3(16, 4), 256, 0, stream>>>(x, 512, fa_in_w + (size_t)i * 786432, 512,
                                                fa_in_b + i * 1536, nullptr, 0, qkv, 1536, 512, 0);
        gemm_k<<<dim3(32, 4), 256, 0, stream>>>(feat_h, 512, fa_in_w + (size_t)i * 786432 + 262144, 512,
                                                fa_in_b + i * 1536 + 512, nullptr, 0, qkv + 512, 1536, 512, 0);
        attn_k<<<32, 256, 0, stream>>>(qkv, attn);
        gemm_k<<<dim3(16, 4), 256, 0, stream>>>(attn, 512, fa_out_w + (size_t)i * 262144, 512,
                                                fa_out_b + i * 512, x, 512, x, 512, 512, 0);

        // FFN
        ln_k<<<128, 256, 0, stream>>>(x, ln3_g + i * 512, ln3_b + i * 512, x);
        gemm_k<<<dim3(64, 4), 256, 0, stream>>>(x, 512, ffn_w1 + (size_t)i * 1048576, 512,
                                                ffn_b1 + i * 2048, nullptr, 0, hid, 2048, 512, 1);
        gemm_k<<<dim3(16, 4), 256, 0, stream>>>(hid, 2048, ffn_w2 + (size_t)i * 1048576, 2048,
                                                ffn_b2 + i * 512, x, 512, q, 512, 2048, 0);
    }
}

// Round 2
// 1854.999 us; speedup vs baseline: 1.5221x; 1.5221x over previous
//
#include <hip/hip_runtime.h>
#include <hip/hip_bf16.h>

typedef __hip_bfloat16 bf16;

#define NQ 128
#define HD 512
#define FD 256
#define NC 6
#define IMH 48
#define IMW 120
#define HW 5760   // 48*120

// ---------------------------------------------------------------------------
// Transpose features (NC, FD, HW) f32  ->  (NC, HW, FD) bf16
// ---------------------------------------------------------------------------
__global__ __launch_bounds__(256) void transpose_feat_k(const float* __restrict__ f,
                                                        bf16* __restrict__ ft)
{
    __shared__ float tile[32][33];
    int cam = blockIdx.z;
    int hw0 = blockIdx.x * 32, fd0 = blockIdx.y * 32;
    int tx = threadIdx.x, ty = threadIdx.y;
    const float* fb = f + (size_t)cam * FD * HW;
    for (int r = ty; r < 32; r += 8)
        tile[r][tx] = fb[(size_t)(fd0 + r) * HW + hw0 + tx];
    __syncthreads();
    bf16* fo = ft + (size_t)cam * HW * FD;
    for (int r = ty; r < 32; r += 8)
        fo[(size_t)(hw0 + r) * FD + fd0 + tx] = __float2bfloat16(tile[tx][r]);
}

// ---------------------------------------------------------------------------
// Generic GEMM: C[m][n] = act( sum_k A[m][k]*W[n][k] + bias[n] ) (+ R[m][n])
// M=128 fixed, tiles 32x32, 256 threads, each thread 4 rows x 1 col.
// ---------------------------------------------------------------------------
__device__ __forceinline__ void gemm_body(const float* __restrict__ A, int lda,
                                          const float* __restrict__ W, int ldw,
                                          const float* __restrict__ bias,
                                          const float* __restrict__ R, int ldr,
                                          float* __restrict__ C, int ldc,
                                          int K, int act, int m0, int n0)
{
    __shared__ float Ast[32 * 36];
    __shared__ float Wst[32 * 36];
    int tid = threadIdx.x;
    int col = tid & 31;
    int rg  = (tid >> 5) * 4;          // base row (0,4,...,28)
    int arow = tid >> 3;               // 0..31
    int ac4  = (tid & 7) << 2;         // 0,4,...,28
    const float* Ald = A + (size_t)(m0 + arow) * lda + ac4;
    const float* Wld = W + (size_t)(n0 + arow) * ldw + ac4;
    float acc[4] = {0.f, 0.f, 0.f, 0.f};

    for (int k0 = 0; k0 < K; k0 += 32) {
        float4 av = *(const float4*)(Ald + k0);
        float4 wv = *(const float4*)(Wld + k0);
        Ast[(ac4 + 0) * 36 + arow] = av.x;
        Ast[(ac4 + 1) * 36 + arow] = av.y;
        Ast[(ac4 + 2) * 36 + arow] = av.z;
        Ast[(ac4 + 3) * 36 + arow] = av.w;
        Wst[(ac4 + 0) * 36 + arow] = wv.x;
        Wst[(ac4 + 1) * 36 + arow] = wv.y;
        Wst[(ac4 + 2) * 36 + arow] = wv.z;
        Wst[(ac4 + 3) * 36 + arow] = wv.w;
        __syncthreads();
#pragma unroll
        for (int k = 0; k < 32; k++) {
            float4 a = *(const float4*)&Ast[k * 36 + rg];
            float  w = Wst[k * 36 + col];
            acc[0] += a.x * w; acc[1] += a.y * w;
            acc[2] += a.z * w; acc[3] += a.w * w;
        }
        __syncthreads();
    }

    float bv = bias[n0 + col];
#pragma unroll
    for (int jj = 0; jj < 4; jj++) {
        int m = m0 + rg + jj;
        float v = acc[jj] + bv;
        if (act == 1) v = fmaxf(v, 0.0f);
        if (R) v += R[(size_t)m * ldr + n0 + col];
        C[(size_t)m * ldc + n0 + col] = v;
    }
}

__global__ __launch_bounds__(256) void gemm_k(const float* __restrict__ A, int lda,
                                              const float* __restrict__ W, int ldw,
                                              const float* __restrict__ bias,
                                              const float* __restrict__ R, int ldr,
                                              float* __restrict__ C, int ldc,
                                              int K, int act)
{
    gemm_body(A, lda, W, ldw, bias, R, ldr, C, ldc, K, act,
              blockIdx.y * 32, blockIdx.x * 32);
}

// fused hidden GEMM for the three prediction heads (motion/type/attr), relu
__global__ __launch_bounds__(256) void gemm3_k(const float* __restrict__ A,
                                               const float* __restrict__ W0, const float* __restrict__ B0,
                                               const float* __restrict__ W1, const float* __restrict__ B1,
                                               const float* __restrict__ W2, const float* __restrict__ B2,
                                               float* __restrict__ C)
{
    int widx = blockIdx.x >> 4;
    const float* W  = (widx == 0) ? W0 : (widx == 1 ? W1 : W2);
    const float* Bv = (widx == 0) ? B0 : (widx == 1 ? B1 : B2);
    gemm_body(A, 512, W, 512, Bv, nullptr, 0, C + widx * 65536, 512, 512, 1,
              blockIdx.y * 32, (blockIdx.x & 15) * 32);
}

// ---------------------------------------------------------------------------
// Head output: out[q][n] = act( hid_row . w2_row + b ), written into d_out
// ---------------------------------------------------------------------------
__global__ __launch_bounds__(64) void heads2_k(const float* __restrict__ hid,
                                               const float* __restrict__ w2m, const float* __restrict__ b2m,
                                               const float* __restrict__ w2t, const float* __restrict__ b2t,
                                               const float* __restrict__ w2a, const float* __restrict__ b2a,
                                               const float* __restrict__ pmin, const float* __restrict__ pmax,
                                               float* __restrict__ out)
{
    int q = blockIdx.x, n = blockIdx.y, lane = threadIdx.x;
    const float* Hp; const float* wr; float bv; int mode;
    if (n < 11)      { Hp = hid;           wr = w2m + n * 512;        bv = b2m[n];      mode = 0; }
    else if (n < 21) { Hp = hid + 65536;   wr = w2t + (n - 11) * 512; bv = b2t[n - 11]; mode = 1; }
    else             { Hp = hid + 131072;  wr = w2a + (n - 21) * 512; bv = b2a[n - 21]; mode = 2; }
    const float4* h4 = (const float4*)(Hp + q * 512);
    const float4* w4 = (const float4*)wr;
    float4 a0 = h4[lane],      c0 = w4[lane];
    float4 a1 = h4[lane + 64], c1 = w4[lane + 64];
    float acc = a0.x * c0.x + a0.y * c0.y + a0.z * c0.z + a0.w * c0.w
              + a1.x * c1.x + a1.y * c1.y + a1.z * c1.z + a1.w * c1.w;
    for (int off = 32; off; off >>= 1) acc += __shfl_xor(acc, off);
    if (lane == 0) {
        float v = acc + bv;
        if (mode == 0)      v = (1.0f / (1.0f + __expf(-v))) * (pmax[n] - pmin[n]) + pmin[n];
        else if (mode == 2) v = 1.0f / (1.0f + __expf(-v));
        out[q * 24 + n] = v;
    }
}

// ---------------------------------------------------------------------------
// LayerNorm over 512 dims, one block per row (in-place safe)
// ---------------------------------------------------------------------------
__global__ __launch_bounds__(256) void ln_k(const float* __restrict__ in,
                                            const float* __restrict__ g,
                                            const float* __restrict__ b,
                                            float* __restrict__ out)
{
    int row = blockIdx.x, tid = threadIdx.x;
    float v0 = in[row * 512 + tid];
    float v1 = in[row * 512 + tid + 256];
    float s = v0 + v1, s2 = v0 * v0 + v1 * v1;
    for (int off = 32; off; off >>= 1) { s += __shfl_xor(s, off); s2 += __shfl_xor(s2, off); }
    __shared__ float sh[8];
    if ((tid & 63) == 0) { sh[tid >> 6] = s; sh[4 + (tid >> 6)] = s2; }
    __syncthreads();
    s  = sh[0] + sh[1] + sh[2] + sh[3];
    s2 = sh[4] + sh[5] + sh[6] + sh[7];
    float mean = s * (1.0f / 512.0f);
    float var  = s2 * (1.0f / 512.0f) - mean * mean;
    float rs = rsqrtf(var + 1e-5f);
    out[row * 512 + tid]       = (v0 - mean) * rs * g[tid] + b[tid];
    out[row * 512 + tid + 256] = (v1 - mean) * rs * g[tid + 256] + b[tid + 256];
}

// ---------------------------------------------------------------------------
// MHA core on a packed qkv buffer (128 x 1536 = [Q|K|V], heads of 64 dims).
// ---------------------------------------------------------------------------
__global__ __launch_bounds__(256) void attn_k(const float* __restrict__ qkv,
                                              float* __restrict__ out)
{
    __shared__ float KVl[128 * 68];   // K[128][68]; later reused as Vt[64][132]
    __shared__ float Ql[32 * 68];
    __shared__ float Pl[32 * 128];
    int h = blockIdx.x >> 2, chunk = blockIdx.x & 3;
    int tid = threadIdx.x;

    for (int l = tid; l < 2048; l += 256) {            // K: 128 rows x 16 float4
        int row = l >> 4, c4 = (l & 15) * 4;
        float4 v = *(const float4*)&qkv[row * 1536 + 512 + h * 64 + c4];
        *(float4*)&KVl[row * 68 + c4] = v;
    }
    for (int l = tid; l < 512; l += 256) {             // Q: 32 rows x 16 float4
        int row = l >> 4, c4 = (l & 15) * 4;
        float4 v = *(const float4*)&qkv[(chunk * 32 + row) * 1536 + h * 64 + c4];
        *(float4*)&Ql[row * 68 + c4] = v;
    }
    __syncthreads();

    int w = tid >> 6, j = tid & 63;
    for (int r8 = 0; r8 < 8; r8++) {
        int lr = w * 8 + r8;
        float s0 = 0.f, s1 = 0.f;
#pragma unroll
        for (int k4 = 0; k4 < 64; k4 += 4) {
            float4 qv  = *(const float4*)&Ql[lr * 68 + k4];
            float4 k0v = *(const float4*)&KVl[j * 68 + k4];
            float4 k1v = *(const float4*)&KVl[(j + 64) * 68 + k4];
            s0 += qv.x * k0v.x + qv.y * k0v.y + qv.z * k0v.z + qv.w * k0v.w;
            s1 += qv.x * k1v.x + qv.y * k1v.y + qv.z * k1v.z + qv.w * k1v.w;
        }
        s0 *= 0.125f; s1 *= 0.125f;
        float m = fmaxf(s0, s1);
        for (int off = 32; off; off >>= 1) m = fmaxf(m, __shfl_xor(m, off));
        float e0 = __expf(s0 - m), e1 = __expf(s1 - m);
        float sm = e0 + e1;
        for (int off = 32; off; off >>= 1) sm += __shfl_xor(sm, off);
        float inv = 1.0f / sm;
        Pl[lr * 128 + j]      = e0 * inv;
        Pl[lr * 128 + j + 64] = e1 * inv;
    }
    __syncthreads();

    for (int l = tid; l < 2048; l += 256) {            // V transposed: Vt[d][row]
        int row = l >> 4, c4 = (l & 15) * 4;
        float4 v = *(const float4*)&qkv[row * 1536 + 1024 + h * 64 + c4];
        KVl[(c4 + 0) * 132 + row] = v.x;
        KVl[(c4 + 1) * 132 + row] = v.y;
        KVl[(c4 + 2) * 132 + row] = v.z;
        KVl[(c4 + 3) * 132 + row] = v.w;
    }
    __syncthreads();

    int d = tid & 63, w2 = tid >> 6;
    for (int r8 = 0; r8 < 8; r8++) {
        int lr = w2 * 8 + r8;
        float o = 0.f;
#pragma unroll
        for (int j4 = 0; j4 < 128; j4 += 4) {
            float4 pv = *(const float4*)&Pl[lr * 128 + j4];
            float4 vv = *(const float4*)&KVl[d * 132 + j4];
            o += pv.x * vv.x + pv.y * vv.y + pv.z * vv.z + pv.w * vv.w;
        }
        out[(chunk * 32 + lr) * 512 + h * 64 + d] = o;
    }
}

// ---------------------------------------------------------------------------
// Gather v2: grid (128 queries, 6 cams), 256 threads.
// Phase 1: 96 point projections -> compacted nonzero (offset,weight) taps in
//          LDS (removes the data-dependent branch from the hot loop).
// Phase 2: thread (g = tid&31, row = tid>>5) accumulates channels g*8..g*8+7
//          over taps row, row+8, ... via one 16B uint4 (8x bf16) load per tap.
// Epilogue: LDS reduce over 8 rows, one atomicAdd per channel (scale 1/576).
// agg must be zeroed before the first cam block runs (hipMemsetAsync).
// ---------------------------------------------------------------------------
__device__ __forceinline__ float bflo(unsigned u) {
    union { unsigned i; float f; } c; c.i = u << 16; return c.f;
}
__device__ __forceinline__ float bfhi(unsigned u) {
    union { unsigned i; float f; } c; c.i = u & 0xffff0000u; return c.f;
}

__global__ __launch_bounds__(256) void gather_k(const bf16* __restrict__ ft,
                                                const float* __restrict__ proj,
                                                const float* __restrict__ preds,
                                                float* __restrict__ agg)
{
    __shared__ float mo[11];
    __shared__ int   goff[384];
    __shared__ float gw[384];
    __shared__ int   cnt;
    __shared__ float part[8][256];
    int n = blockIdx.x, cam = blockIdx.y, tid = threadIdx.x;
    if (tid == 0) cnt = 0;
    if (tid < 11) mo[tid] = preds[n * 24 + tid];
    __syncthreads();

    if (tid < 96) {
        int p = tid;
        float dd0 = mo[8], dd1 = mo[9], dd2 = mo[10];
        float c0 = mo[0], c1 = mo[1], c2 = mo[2];
        float sy, cy;
        sincosf(mo[7], &sy, &cy);
        int face = p >> 4, axis = face >> 1;
        float sgn = (face & 1) ? 0.5f : -0.5f;
        float offi = -0.4f + (float)((p >> 2) & 3) * (0.8f / 3.0f);
        float offj = -0.4f + (float)(p & 3) * (0.8f / 3.0f);
        float t0, t1, t2;
        if (axis == 0)      { t0 = sgn;  t1 = offi; t2 = offj; }
        else if (axis == 1) { t0 = offi; t1 = sgn;  t2 = offj; }
        else                { t0 = offi; t1 = offj; t2 = sgn;  }
        float px = t0 * dd0, py = t1 * dd1, pz = t2 * dd2;
        float X = px * cy - py * sy + c0;
        float Y = px * sy + py * cy + c1;
        float Z = pz + c2;
        const float* P = proj + cam * 12;
        float cu = P[0] * X + P[1] * Y + P[2] * Z + P[3];
        float cv = P[4] * X + P[5] * Y + P[6] * Z + P[7];
        float cz = P[8] * X + P[9] * Y + P[10] * Z + P[11];
        float zs = (fabsf(cz) > 1e-6f) ? cz : 1e-6f;
        float u = cu / zs, v = cv / zs;
        bool front = cz > 0.0f;
        float u0 = floorf(u), v0 = floorf(v);
        float du = u - u0, dv = v - v0;
        float us[4] = {u0, u0 + 1.0f, u0, u0 + 1.0f};
        float vs[4] = {v0, v0, v0 + 1.0f, v0 + 1.0f};
        float wt[4] = {(1.0f - du) * (1.0f - dv), du * (1.0f - dv),
                       (1.0f - du) * dv, du * dv};
        int   myoff[4]; float myw[4]; int k = 0;
#pragma unroll
        for (int t = 0; t < 4; t++) {
            bool ok = front && (us[t] >= 0.0f) && (us[t] <= 119.0f)
                            && (vs[t] >= 0.0f) && (vs[t] <= 47.0f)
                            && (wt[t] > 0.0f);
            if (ok) {
                myoff[k] = ((int)vs[t] * IMW + (int)us[t]) * FD;
                myw[k]   = wt[t];
                k++;
            }
        }
        if (k) {
            int base = atomicAdd(&cnt, k);
            for (int s = 0; s < k; s++) { goff[base + s] = myoff[s]; gw[base + s] = myw[s]; }
        }
    }
    __syncthreads();
    int C = cnt;
    if (C == 0) return;   // uniform: whole (query,cam) invisible

    int g8  = (tid & 31) * 8;   // channel base
    int row = tid >> 5;         // 0..7, tap phase
    const bf16* fb = ft + (size_t)cam * HW * FD + g8;
    float acc[8] = {0.f, 0.f, 0.f, 0.f, 0.f, 0.f, 0.f, 0.f};
    for (int e = row; e < C; e += 8) {
        float w = gw[e];
        uint4 rv = *(const uint4*)(fb + goff[e]);
        acc[0] += w * bflo(rv.x); acc[1] += w * bfhi(rv.x);
        acc[2] += w * bflo(rv.y); acc[3] += w * bfhi(rv.y);
        acc[4] += w * bflo(rv.z); acc[5] += w * bfhi(rv.z);
        acc[6] += w * bflo(rv.w); acc[7] += w * bfhi(rv.w);
    }
#pragma unroll
    for (int j = 0; j < 8; j++) part[row][g8 + j] = acc[j];
    __syncthreads();
    float s = 0.f;
#pragma unroll
    for (int r = 0; r < 8; r++) s += part[r][tid];
    atomicAdd(&agg[n * 256 + tid], s * (1.0f / 576.0f));
}

// ---------------------------------------------------------------------------
extern "C" void kernel_launch(void* const* d_in, const int* in_sizes, int n_in,
                              void* d_out, int out_size, void* d_ws, size_t ws_size,
                              hipStream_t stream)
{
    const float* features  = (const float*)d_in[0];
    const float* proj      = (const float*)d_in[1];
    const float* queries0  = (const float*)d_in[3];
    const float* pmin      = (const float*)d_in[4];
    const float* pmax      = (const float*)d_in[5];
    const float* motion_w1 = (const float*)d_in[6];
    const float* motion_b1 = (const float*)d_in[7];
    const float* motion_w2 = (const float*)d_in[8];
    const float* motion_b2 = (const float*)d_in[9];
    const float* type_w1   = (const float*)d_in[10];
    const float* type_b1   = (const float*)d_in[11];
    const float* type_w2   = (const float*)d_in[12];
    const float* type_b2   = (const float*)d_in[13];
    const float* attr_w1   = (const float*)d_in[14];
    const float* attr_b1   = (const float*)d_in[15];
    const float* attr_w2   = (const float*)d_in[16];
    const float* attr_b2   = (const float*)d_in[17];
    const float* fmlp_w1   = (const float*)d_in[18];
    const float* fmlp_b1   = (const float*)d_in[19];
    const float* fmlp_w2   = (const float*)d_in[20];
    const float* fmlp_b2   = (const float*)d_in[21];
    const float* sa_in_w   = (const float*)d_in[22];
    const float* sa_in_b   = (const float*)d_in[23];
    const float* sa_out_w  = (const float*)d_in[24];
    const float* sa_out_b  = (const float*)d_in[25];
    const float* fa_in_w   = (const float*)d_in[26];
    const float* fa_in_b   = (const float*)d_in[27];
    const float* fa_out_w  = (const float*)d_in[28];
    const float* fa_out_b  = (const float*)d_in[29];
    const float* ffn_w1    = (const float*)d_in[30];
    const float* ffn_b1    = (const float*)d_in[31];
    const float* ffn_w2    = (const float*)d_in[32];
    const float* ffn_b2    = (const float*)d_in[33];
    const float* ln1_g     = (const float*)d_in[34];
    const float* ln1_b     = (const float*)d_in[35];
    const float* ln2_g     = (const float*)d_in[36];
    const float* ln2_b     = (const float*)d_in[37];
    const float* ln3_g     = (const float*)d_in[38];
    const float* ln3_b     = (const float*)d_in[39];
    float* out = (float*)d_out;

    // workspace layout
    char* wsb = (char*)d_ws;
    bf16* feat_t = (bf16*)wsb;                       // 6*5760*256 bf16 = 17,694,720 B
    float* fbase = (float*)(wsb + (size_t)NC * HW * FD * sizeof(bf16));
    float* q      = fbase;                 // 128*512
    float* x      = q + 65536;             // 128*512
    float* qkv    = x + 65536;             // 128*1536
    float* attn   = qkv + 196608;          // 128*512
    float* hid    = attn + 65536;          // 128*2048 (also 3 head-hidden slabs)
    float* agg    = hid + 262144;          // 128*256
    float* feat_h = agg + 32768;           // 128*512

    transpose_feat_k<<<dim3(180, 8, 6), dim3(32, 8), 0, stream>>>(features, feat_t);
    hipMemcpyAsync(q, queries0, 65536 * sizeof(float), hipMemcpyDeviceToDevice, stream);

    for (int i = 0; i < 6; i++) {
        // prediction heads (read q as-is)
        gemm3_k<<<dim3(48, 4), 256, 0, stream>>>(q, motion_w1, motion_b1,
                                                 type_w1, type_b1, attr_w1, attr_b1, hid);
        heads2_k<<<dim3(128, 24), 64, 0, stream>>>(hid, motion_w2, motion_b2,
                                                   type_w2, type_b2, attr_w2, attr_b2,
                                                   pmin, pmax, out + i * 3072);
        if (i == 5) break;

        // deformable-style feature gather (reads motion params from d_out)
        hipMemsetAsync(agg, 0, 128 * 256 * sizeof(float), stream);
        gather_k<<<dim3(128, 6), 256, 0, stream>>>(feat_t, proj, out + i * 3072, agg);
        gemm_k<<<dim3(16, 4), 256, 0, stream>>>(agg, 256, fmlp_w1, 256, fmlp_b1,
                                                nullptr, 0, hid, 512, 256, 1);
        gemm_k<<<dim3(16, 4), 256, 0, stream>>>(hid, 512, fmlp_w2, 512, fmlp_b2,
                                                nullptr, 0, feat_h, 512, 512, 0);

        // self-attention
        ln_k<<<128, 256, 0, stream>>>(q, ln1_g + i * 512, ln1_b + i * 512, x);
        gemm_k<<<dim3(48, 4), 256, 0, stream>>>(x, 512, sa_in_w + (size_t)i * 786432, 512,
                                                sa_in_b + i * 1536, nullptr, 0, qkv, 1536, 512, 0);
        attn_k<<<32, 256, 0, stream>>>(qkv, attn);
        gemm_k<<<dim3(16, 4), 256, 0, stream>>>(attn, 512, sa_out_w + (size_t)i * 262144, 512,
                                                sa_out_b + i * 512, x, 512, x, 512, 512, 0);

        // cross-attention (Q from x, K/V from feat_h)
        ln_k<<<128, 256, 0, stream>>>(x, ln2_g + i * 512, ln2_b + i * 512, x);
        gemm_k<<<dim3(16, 4), 256, 0, stream>>>(x, 512, fa_in_w + (size_t)i * 786432, 512,
                                                fa_in_b + i * 1536, nullptr, 0, qkv, 1536, 512, 0);
        gemm_k<<<dim3(32, 4), 256, 0, stream>>>(feat_h, 512, fa_in_w + (size_t)i * 786432 + 262144, 512,
                                                fa_in_b + i * 1536 + 512, nullptr, 0, qkv + 512, 1536, 512, 0);
        attn_k<<<32, 256, 0, stream>>>(qkv, attn);
        gemm_k<<<dim3(16, 4), 256, 0, stream>>>(attn, 512, fa_out_w + (size_t)i * 262144, 512,
                                                fa_out_b + i * 512, x, 512, x, 512, 512, 0);

        // FFN
        ln_k<<<128, 256, 0, stream>>>(x, ln3_g + i * 512, ln3_b + i * 512, x);
        gemm_k<<<dim3(64, 4), 256, 0, stream>>>(x, 512, ffn_w1 + (size_t)i * 1048576, 512,
                                                ffn_b1 + i * 2048, nullptr, 0, hid, 2048, 512, 1);
        gemm_k<<<dim3(16, 4), 256, 0, stream>>>(hid, 2048, ffn_w2 + (size_t)i * 1048576, 2048,
                                                ffn_b2 + i * 512, x, 512, q, 512, 2048, 0);
    }
}

// Round 3
// 997.267 us; speedup vs baseline: 2.8312x; 1.8601x over previous
//
#include <hip/hip_runtime.h>
#include <hip/hip_bf16.h>

typedef __hip_bfloat16 bf16;
typedef __attribute__((ext_vector_type(8))) _Float16 half8;
typedef __attribute__((ext_vector_type(4))) float f32x4;

#define NQ 128
#define HD 512
#define FD 256
#define NC 6
#define IMH 48
#define IMW 120
#define HW 5760   // 48*120

// ---------------------------------------------------------------------------
// Transpose features (NC, FD, HW) f32  ->  (NC, HW, FD) bf16
// ---------------------------------------------------------------------------
__global__ __launch_bounds__(256) void transpose_feat_k(const float* __restrict__ f,
                                                        bf16* __restrict__ ft)
{
    __shared__ float tile[32][33];
    int cam = blockIdx.z;
    int hw0 = blockIdx.x * 32, fd0 = blockIdx.y * 32;
    int tx = threadIdx.x, ty = threadIdx.y;
    const float* fb = f + (size_t)cam * FD * HW;
    for (int r = ty; r < 32; r += 8)
        tile[r][tx] = fb[(size_t)(fd0 + r) * HW + hw0 + tx];
    __syncthreads();
    bf16* fo = ft + (size_t)cam * HW * FD;
    for (int r = ty; r < 32; r += 8)
        fo[(size_t)(hw0 + r) * FD + fd0 + tx] = __float2bfloat16(tile[tx][r]);
}

// ---------------------------------------------------------------------------
// Split-K MFMA GEMM.  C[m][n] += sum_k act(A[m][k]) * W[n][k]  (+bias+R by z==0)
// Block: 64(m) x 64(n) C-tile, K-slice of 128.  grid (N/64, 2, K/128).
// 256 thr = 4 waves; wave w computes rows w*16..w*16+15 x all 64 cols
// via 4x v_mfma_f32_16x16x32_f16 per 32-k step.
// LDS is fragment-major: frag (kstep s, rowblk b) at [( s*4+b )*64 + lane]*8
// halfs, so frag load = ds_read_b128 at lane*16B (canonical, conflict-free).
// A and W are fp32 in global; converted to fp16 while staging.
// Outputs accumulated with atomicAdd into a pre-zeroed arena.
// ---------------------------------------------------------------------------
__device__ __forceinline__ float4 relu4(float4 v) {
    v.x = fmaxf(v.x, 0.f); v.y = fmaxf(v.y, 0.f);
    v.z = fmaxf(v.z, 0.f); v.w = fmaxf(v.w, 0.f);
    return v;
}

__device__ __forceinline__ void stash16(_Float16* dst, int rb, int lo, int kc,
                                        float4 x, float4 y)
{
    int s = kc >> 2, hi = kc & 3;
    half8 h;
    h[0] = (_Float16)x.x; h[1] = (_Float16)x.y; h[2] = (_Float16)x.z; h[3] = (_Float16)x.w;
    h[4] = (_Float16)y.x; h[5] = (_Float16)y.y; h[6] = (_Float16)y.z; h[7] = (_Float16)y.w;
    *(half8*)&dst[(size_t)(((s * 4 + rb) * 64 + hi * 16 + lo)) * 8] = h;
}

__device__ __forceinline__ void gemm_mfma_body(const float* __restrict__ A, int lda,
                                               const float* __restrict__ W, int ldw,
                                               const float* __restrict__ bias,
                                               const float* __restrict__ R, int ldr,
                                               float* __restrict__ C, int ldc,
                                               int reluA, int m0, int n0, int k0,
                                               bool split0)
{
    __shared__ _Float16 Al[8192];   // 4 ksteps x 4 rowblks x 64 lanes x 8 halfs
    __shared__ _Float16 Bl[8192];
    int tid = threadIdx.x;
    int row8 = tid >> 3;            // 0..31
    int kc2  = (tid & 7) * 2;       // chunk pair (8 halfs per chunk)

#pragma unroll
    for (int rr = 0; rr < 2; rr++) {
        int m = row8 + rr * 32;
        const float4* ap = (const float4*)(A + (size_t)(m0 + m) * lda + k0 + kc2 * 8);
        float4 a0 = ap[0], a1 = ap[1], a2 = ap[2], a3 = ap[3];
        const float4* wp = (const float4*)(W + (size_t)(n0 + m) * ldw + k0 + kc2 * 8);
        float4 w0 = wp[0], w1 = wp[1], w2 = wp[2], w3 = wp[3];
        if (reluA) { a0 = relu4(a0); a1 = relu4(a1); a2 = relu4(a2); a3 = relu4(a3); }
        stash16(Al, m >> 4, m & 15, kc2,     a0, a1);
        stash16(Al, m >> 4, m & 15, kc2 + 1, a2, a3);
        stash16(Bl, m >> 4, m & 15, kc2,     w0, w1);
        stash16(Bl, m >> 4, m & 15, kc2 + 1, w2, w3);
    }
    __syncthreads();

    int l = tid & 63, wv = tid >> 6;
    f32x4 acc[4];
#pragma unroll
    for (int ct = 0; ct < 4; ct++) acc[ct] = (f32x4){0.f, 0.f, 0.f, 0.f};

#pragma unroll
    for (int s = 0; s < 4; s++) {
        half8 a = *(const half8*)&Al[(size_t)((s * 4 + wv) * 64 + l) * 8];
#pragma unroll
        for (int ct = 0; ct < 4; ct++) {
            half8 b = *(const half8*)&Bl[(size_t)((s * 4 + ct) * 64 + l) * 8];
            acc[ct] = __builtin_amdgcn_mfma_f32_16x16x32_f16(a, b, acc[ct], 0, 0, 0);
        }
    }

    int quad = l >> 4, cn = l & 15;
#pragma unroll
    for (int ct = 0; ct < 4; ct++) {
        int n = n0 + ct * 16 + cn;
        float bv = split0 ? bias[n] : 0.f;
#pragma unroll
        for (int r = 0; r < 4; r++) {
            int m = m0 + wv * 16 + quad * 4 + r;
            float v = acc[ct][r];
            if (split0) {
                v += bv;
                if (R) v += R[(size_t)m * ldr + n];
            }
            atomicAdd(&C[(size_t)m * ldc + n], v);
        }
    }
}

__global__ __launch_bounds__(256) void gemm_sk(const float* __restrict__ A, int lda,
                                               const float* __restrict__ W, int ldw,
                                               const float* __restrict__ bias,
                                               const float* __restrict__ R, int ldr,
                                               float* __restrict__ C, int ldc,
                                               int reluA)
{
    gemm_mfma_body(A, lda, W, ldw, bias, R, ldr, C, ldc, reluA,
                   blockIdx.y * 64, blockIdx.x * 64, blockIdx.z * 128,
                   blockIdx.z == 0);
}

// fused hidden GEMM for the three prediction heads (linear; relu in consumer)
__global__ __launch_bounds__(256) void gemm3_sk(const float* __restrict__ A,
                                                const float* __restrict__ W0, const float* __restrict__ B0,
                                                const float* __restrict__ W1, const float* __restrict__ B1,
                                                const float* __restrict__ W2, const float* __restrict__ B2,
                                                float* __restrict__ C)
{
    int widx = blockIdx.x >> 3;
    const float* W  = (widx == 0) ? W0 : (widx == 1 ? W1 : W2);
    const float* Bv = (widx == 0) ? B0 : (widx == 1 ? B1 : B2);
    gemm_mfma_body(A, 512, W, 512, Bv, nullptr, 0, C + widx * 65536, 512, 0,
                   blockIdx.y * 64, (blockIdx.x & 7) * 64, blockIdx.z * 128,
                   blockIdx.z == 0);
}

// ---------------------------------------------------------------------------
// Head output: out[q][n] = act( relu(hid_row) . w2_row + b ), into d_out
// ---------------------------------------------------------------------------
__global__ __launch_bounds__(64) void heads2_k(const float* __restrict__ hid,
                                               const float* __restrict__ w2m, const float* __restrict__ b2m,
                                               const float* __restrict__ w2t, const float* __restrict__ b2t,
                                               const float* __restrict__ w2a, const float* __restrict__ b2a,
                                               const float* __restrict__ pmin, const float* __restrict__ pmax,
                                               float* __restrict__ out)
{
    int q = blockIdx.x, n = blockIdx.y, lane = threadIdx.x;
    const float* Hp; const float* wr; float bv; int mode;
    if (n < 11)      { Hp = hid;           wr = w2m + n * 512;        bv = b2m[n];      mode = 0; }
    else if (n < 21) { Hp = hid + 65536;   wr = w2t + (n - 11) * 512; bv = b2t[n - 11]; mode = 1; }
    else             { Hp = hid + 131072;  wr = w2a + (n - 21) * 512; bv = b2a[n - 21]; mode = 2; }
    const float4* h4 = (const float4*)(Hp + q * 512);
    const float4* w4 = (const float4*)wr;
    float4 a0 = relu4(h4[lane]),      c0 = w4[lane];
    float4 a1 = relu4(h4[lane + 64]), c1 = w4[lane + 64];
    float acc = a0.x * c0.x + a0.y * c0.y + a0.z * c0.z + a0.w * c0.w
              + a1.x * c1.x + a1.y * c1.y + a1.z * c1.z + a1.w * c1.w;
    for (int off = 32; off; off >>= 1) acc += __shfl_xor(acc, off);
    if (lane == 0) {
        float v = acc + bv;
        if (mode == 0)      v = (1.0f / (1.0f + __expf(-v))) * (pmax[n] - pmin[n]) + pmin[n];
        else if (mode == 2) v = 1.0f / (1.0f + __expf(-v));
        out[q * 24 + n] = v;
    }
}

// ---------------------------------------------------------------------------
// LayerNorm over 512 dims, one block per row
// ---------------------------------------------------------------------------
__global__ __launch_bounds__(256) void ln_k(const float* __restrict__ in,
                                            const float* __restrict__ g,
                                            const float* __restrict__ b,
                                            float* __restrict__ out)
{
    int row = blockIdx.x, tid = threadIdx.x;
    float v0 = in[row * 512 + tid];
    float v1 = in[row * 512 + tid + 256];
    float s = v0 + v1, s2 = v0 * v0 + v1 * v1;
    for (int off = 32; off; off >>= 1) { s += __shfl_xor(s, off); s2 += __shfl_xor(s2, off); }
    __shared__ float sh[8];
    if ((tid & 63) == 0) { sh[tid >> 6] = s; sh[4 + (tid >> 6)] = s2; }
    __syncthreads();
    s  = sh[0] + sh[1] + sh[2] + sh[3];
    s2 = sh[4] + sh[5] + sh[6] + sh[7];
    float mean = s * (1.0f / 512.0f);
    float var  = s2 * (1.0f / 512.0f) - mean * mean;
    float rs = rsqrtf(var + 1e-5f);
    out[row * 512 + tid]       = (v0 - mean) * rs * g[tid] + b[tid];
    out[row * 512 + tid + 256] = (v1 - mean) * rs * g[tid + 256] + b[tid + 256];
}

// ---------------------------------------------------------------------------
// MHA core on a packed qkv buffer (128 x 1536 = [Q|K|V], heads of 64 dims).
// ---------------------------------------------------------------------------
__global__ __launch_bounds__(256) void attn_k(const float* __restrict__ qkv,
                                              float* __restrict__ out)
{
    __shared__ float KVl[128 * 68];   // K[128][68]; later reused as Vt[64][132]
    __shared__ float Ql[32 * 68];
    __shared__ float Pl[32 * 128];
    int h = blockIdx.x >> 2, chunk = blockIdx.x & 3;
    int tid = threadIdx.x;

    for (int l = tid; l < 2048; l += 256) {            // K: 128 rows x 16 float4
        int row = l >> 4, c4 = (l & 15) * 4;
        float4 v = *(const float4*)&qkv[row * 1536 + 512 + h * 64 + c4];
        *(float4*)&KVl[row * 68 + c4] = v;
    }
    for (int l = tid; l < 512; l += 256) {             // Q: 32 rows x 16 float4
        int row = l >> 4, c4 = (l & 15) * 4;
        float4 v = *(const float4*)&qkv[(chunk * 32 + row) * 1536 + h * 64 + c4];
        *(float4*)&Ql[row * 68 + c4] = v;
    }
    __syncthreads();

    int w = tid >> 6, j = tid & 63;
    for (int r8 = 0; r8 < 8; r8++) {
        int lr = w * 8 + r8;
        float s0 = 0.f, s1 = 0.f;
#pragma unroll
        for (int k4 = 0; k4 < 64; k4 += 4) {
            float4 qv  = *(const float4*)&Ql[lr * 68 + k4];
            float4 k0v = *(const float4*)&KVl[j * 68 + k4];
            float4 k1v = *(const float4*)&KVl[(j + 64) * 68 + k4];
            s0 += qv.x * k0v.x + qv.y * k0v.y + qv.z * k0v.z + qv.w * k0v.w;
            s1 += qv.x * k1v.x + qv.y * k1v.y + qv.z * k1v.z + qv.w * k1v.w;
        }
        s0 *= 0.125f; s1 *= 0.125f;
        float m = fmaxf(s0, s1);
        for (int off = 32; off; off >>= 1) m = fmaxf(m, __shfl_xor(m, off));
        float e0 = __expf(s0 - m), e1 = __expf(s1 - m);
        float sm = e0 + e1;
        for (int off = 32; off; off >>= 1) sm += __shfl_xor(sm, off);
        float inv = 1.0f / sm;
        Pl[lr * 128 + j]      = e0 * inv;
        Pl[lr * 128 + j + 64] = e1 * inv;
    }
    __syncthreads();

    for (int l = tid; l < 2048; l += 256) {            // V transposed: Vt[d][row]
        int row = l >> 4, c4 = (l & 15) * 4;
        float4 v = *(const float4*)&qkv[row * 1536 + 1024 + h * 64 + c4];
        KVl[(c4 + 0) * 132 + row] = v.x;
        KVl[(c4 + 1) * 132 + row] = v.y;
        KVl[(c4 + 2) * 132 + row] = v.z;
        KVl[(c4 + 3) * 132 + row] = v.w;
    }
    __syncthreads();

    int d = tid & 63, w2 = tid >> 6;
    for (int r8 = 0; r8 < 8; r8++) {
        int lr = w2 * 8 + r8;
        float o = 0.f;
#pragma unroll
        for (int j4 = 0; j4 < 128; j4 += 4) {
            float4 pv = *(const float4*)&Pl[lr * 128 + j4];
            float4 vv = *(const float4*)&KVl[d * 132 + j4];
            o += pv.x * vv.x + pv.y * vv.y + pv.z * vv.z + pv.w * vv.w;
        }
        out[(chunk * 32 + lr) * 512 + h * 64 + d] = o;
    }
}

// ---------------------------------------------------------------------------
// Gather: grid (128 queries, 6 cams), 256 threads. Compacted taps + 8ch/thread.
// ---------------------------------------------------------------------------
__device__ __forceinline__ float bflo(unsigned u) {
    union { unsigned i; float f; } c; c.i = u << 16; return c.f;
}
__device__ __forceinline__ float bfhi(unsigned u) {
    union { unsigned i; float f; } c; c.i = u & 0xffff0000u; return c.f;
}

__global__ __launch_bounds__(256) void gather_k(const bf16* __restrict__ ft,
                                                const float* __restrict__ proj,
                                                const float* __restrict__ preds,
                                                float* __restrict__ agg)
{
    __shared__ float mo[11];
    __shared__ int   goff[384];
    __shared__ float gw[384];
    __shared__ int   cnt;
    __shared__ float part[8][256];
    int n = blockIdx.x, cam = blockIdx.y, tid = threadIdx.x;
    if (tid == 0) cnt = 0;
    if (tid < 11) mo[tid] = preds[n * 24 + tid];
    __syncthreads();

    if (tid < 96) {
        int p = tid;
        float dd0 = mo[8], dd1 = mo[9], dd2 = mo[10];
        float c0 = mo[0], c1 = mo[1], c2 = mo[2];
        float sy, cy;
        sincosf(mo[7], &sy, &cy);
        int face = p >> 4, axis = face >> 1;
        float sgn = (face & 1) ? 0.5f : -0.5f;
        float offi = -0.4f + (float)((p >> 2) & 3) * (0.8f / 3.0f);
        float offj = -0.4f + (float)(p & 3) * (0.8f / 3.0f);
        float t0, t1, t2;
        if (axis == 0)      { t0 = sgn;  t1 = offi; t2 = offj; }
        else if (axis == 1) { t0 = offi; t1 = sgn;  t2 = offj; }
        else                { t0 = offi; t1 = offj; t2 = sgn;  }
        float px = t0 * dd0, py = t1 * dd1, pz = t2 * dd2;
        float X = px * cy - py * sy + c0;
        float Y = px * sy + py * cy + c1;
        float Z = pz + c2;
        const float* P = proj + cam * 12;
        float cu = P[0] * X + P[1] * Y + P[2] * Z + P[3];
        float cv = P[4] * X + P[5] * Y + P[6] * Z + P[7];
        float cz = P[8] * X + P[9] * Y + P[10] * Z + P[11];
        float zs = (fabsf(cz) > 1e-6f) ? cz : 1e-6f;
        float u = cu / zs, v = cv / zs;
        bool front = cz > 0.0f;
        float u0 = floorf(u), v0 = floorf(v);
        float du = u - u0, dv = v - v0;
        float us[4] = {u0, u0 + 1.0f, u0, u0 + 1.0f};
        float vs[4] = {v0, v0, v0 + 1.0f, v0 + 1.0f};
        float wt[4] = {(1.0f - du) * (1.0f - dv), du * (1.0f - dv),
                       (1.0f - du) * dv, du * dv};
        int   myoff[4]; float myw[4]; int k = 0;
#pragma unroll
        for (int t = 0; t < 4; t++) {
            bool ok = front && (us[t] >= 0.0f) && (us[t] <= 119.0f)
                            && (vs[t] >= 0.0f) && (vs[t] <= 47.0f)
                            && (wt[t] > 0.0f);
            if (ok) {
                myoff[k] = ((int)vs[t] * IMW + (int)us[t]) * FD;
                myw[k]   = wt[t];
                k++;
            }
        }
        if (k) {
            int base = atomicAdd(&cnt, k);
            for (int s = 0; s < k; s++) { goff[base + s] = myoff[s]; gw[base + s] = myw[s]; }
        }
    }
    __syncthreads();
    int C = cnt;
    if (C == 0) return;

    int g8  = (tid & 31) * 8;
    int row = tid >> 5;
    const bf16* fb = ft + (size_t)cam * HW * FD + g8;
    float acc[8] = {0.f, 0.f, 0.f, 0.f, 0.f, 0.f, 0.f, 0.f};
    for (int e = row; e < C; e += 8) {
        float w = gw[e];
        uint4 rv = *(const uint4*)(fb + goff[e]);
        acc[0] += w * bflo(rv.x); acc[1] += w * bfhi(rv.x);
        acc[2] += w * bflo(rv.y); acc[3] += w * bfhi(rv.y);
        acc[4] += w * bflo(rv.z); acc[5] += w * bfhi(rv.z);
        acc[6] += w * bflo(rv.w); acc[7] += w * bfhi(rv.w);
    }
#pragma unroll
    for (int j = 0; j < 8; j++) part[row][g8 + j] = acc[j];
    __syncthreads();
    float s = 0.f;
#pragma unroll
    for (int r = 0; r < 8; r++) s += part[r][tid];
    atomicAdd(&agg[n * 256 + tid], s * (1.0f / 576.0f));
}

// ---------------------------------------------------------------------------
// Arena (floats, per layer, zeroed once per layer):
#define O_HID3   0          // 128x1536  (pre-relu head hiddens)
#define O_AGG    196608     // 128x256
#define O_FMLPH  229376     // 128x512   (pre-relu)
#define O_FEATH  294912     // 128x512
#define O_QKVSA  360448     // 128x1536
#define O_X1     557056     // 128x512
#define O_QKVFA  622592     // 128x1536
#define O_X2     819200     // 128x512
#define O_FFNH   884736     // 128x2048  (pre-relu)
#define O_QNEXT  1146880    // 128x512
#define ARENA_FLOATS 1212416

extern "C" void kernel_launch(void* const* d_in, const int* in_sizes, int n_in,
                              void* d_out, int out_size, void* d_ws, size_t ws_size,
                              hipStream_t stream)
{
    const float* features  = (const float*)d_in[0];
    const float* proj      = (const float*)d_in[1];
    const float* queries0  = (const float*)d_in[3];
    const float* pmin      = (const float*)d_in[4];
    const float* pmax      = (const float*)d_in[5];
    const float* motion_w1 = (const float*)d_in[6];
    const float* motion_b1 = (const float*)d_in[7];
    const float* motion_w2 = (const float*)d_in[8];
    const float* motion_b2 = (const float*)d_in[9];
    const float* type_w1   = (const float*)d_in[10];
    const float* type_b1   = (const float*)d_in[11];
    const float* type_w2   = (const float*)d_in[12];
    const float* type_b2   = (const float*)d_in[13];
    const float* attr_w1   = (const float*)d_in[14];
    const float* attr_b1   = (const float*)d_in[15];
    const float* attr_w2   = (const float*)d_in[16];
    const float* attr_b2   = (const float*)d_in[17];
    const float* fmlp_w1   = (const float*)d_in[18];
    const float* fmlp_b1   = (const float*)d_in[19];
    const float* fmlp_w2   = (const float*)d_in[20];
    const float* fmlp_b2   = (const float*)d_in[21];
    const float* sa_in_w   = (const float*)d_in[22];
    const float* sa_in_b   = (const float*)d_in[23];
    const float* sa_out_w  = (const float*)d_in[24];
    const float* sa_out_b  = (const float*)d_in[25];
    const float* fa_in_w   = (const float*)d_in[26];
    const float* fa_in_b   = (const float*)d_in[27];
    const float* fa_out_w  = (const float*)d_in[28];
    const float* fa_out_b  = (const float*)d_in[29];
    const float* ffn_w1    = (const float*)d_in[30];
    const float* ffn_b1    = (const float*)d_in[31];
    const float* ffn_w2    = (const float*)d_in[32];
    const float* ffn_b2    = (const float*)d_in[33];
    const float* ln1_g     = (const float*)d_in[34];
    const float* ln1_b     = (const float*)d_in[35];
    const float* ln2_g     = (const float*)d_in[36];
    const float* ln2_b     = (const float*)d_in[37];
    const float* ln3_g     = (const float*)d_in[38];
    const float* ln3_b     = (const float*)d_in[39];
    float* out = (float*)d_out;

    // workspace layout
    char* wsb = (char*)d_ws;
    bf16* feat_t = (bf16*)wsb;                       // 6*5760*256 bf16 = 17,694,720 B
    float* fbase  = (float*)(wsb + (size_t)NC * HW * FD * sizeof(bf16));
    float* lnx    = fbase;                  // 128*512
    float* attnb  = lnx + 65536;            // 128*512
    float* arena0 = attnb + 65536;
    float* arena1 = arena0 + ARENA_FLOATS;

    transpose_feat_k<<<dim3(180, 8, 6), dim3(32, 8), 0, stream>>>(features, feat_t);

    const float* qcur = queries0;           // layer-0 queries read directly
    for (int i = 0; i < 6; i++) {
        float* ar = (i & 1) ? arena1 : arena0;
        hipMemsetAsync(ar, 0, ARENA_FLOATS * sizeof(float), stream);

        // prediction heads
        gemm3_sk<<<dim3(24, 2, 4), 256, 0, stream>>>(qcur, motion_w1, motion_b1,
                                                     type_w1, type_b1, attr_w1, attr_b1,
                                                     ar + O_HID3);
        heads2_k<<<dim3(128, 24), 64, 0, stream>>>(ar + O_HID3, motion_w2, motion_b2,
                                                   type_w2, type_b2, attr_w2, attr_b2,
                                                   pmin, pmax, out + i * 3072);
        if (i == 5) break;

        // feature gather + feature MLP
        gather_k<<<dim3(128, 6), 256, 0, stream>>>(feat_t, proj, out + i * 3072, ar + O_AGG);
        gemm_sk<<<dim3(8, 2, 2), 256, 0, stream>>>(ar + O_AGG, 256, fmlp_w1, 256, fmlp_b1,
                                                   nullptr, 0, ar + O_FMLPH, 512, 0);
        gemm_sk<<<dim3(8, 2, 4), 256, 0, stream>>>(ar + O_FMLPH, 512, fmlp_w2, 512, fmlp_b2,
                                                   nullptr, 0, ar + O_FEATH, 512, 1);

        // self-attention
        ln_k<<<128, 256, 0, stream>>>(qcur, ln1_g + i * 512, ln1_b + i * 512, lnx);
        gemm_sk<<<dim3(24, 2, 4), 256, 0, stream>>>(lnx, 512, sa_in_w + (size_t)i * 786432, 512,
                                                    sa_in_b + i * 1536, nullptr, 0,
                                                    ar + O_QKVSA, 1536, 0);
        attn_k<<<32, 256, 0, stream>>>(ar + O_QKVSA, attnb);
        gemm_sk<<<dim3(8, 2, 4), 256, 0, stream>>>(attnb, 512, sa_out_w + (size_t)i * 262144, 512,
                                                   sa_out_b + i * 512, lnx, 512,
                                                   ar + O_X1, 512, 0);

        // cross-attention
        ln_k<<<128, 256, 0, stream>>>(ar + O_X1, ln2_g + i * 512, ln2_b + i * 512, lnx);
        gemm_sk<<<dim3(8, 2, 4), 256, 0, stream>>>(lnx, 512, fa_in_w + (size_t)i * 786432, 512,
                                                   fa_in_b + i * 1536, nullptr, 0,
                                                   ar + O_QKVFA, 1536, 0);
        gemm_sk<<<dim3(16, 2, 4), 256, 0, stream>>>(ar + O_FEATH, 512,
                                                    fa_in_w + (size_t)i * 786432 + 262144, 512,
                                                    fa_in_b + i * 1536 + 512, nullptr, 0,
                                                    ar + O_QKVFA + 512, 1536, 0);
        attn_k<<<32, 256, 0, stream>>>(ar + O_QKVFA, attnb);
        gemm_sk<<<dim3(8, 2, 4), 256, 0, stream>>>(attnb, 512, fa_out_w + (size_t)i * 262144, 512,
                                                   fa_out_b + i * 512, lnx, 512,
                                                   ar + O_X2, 512, 0);

        // FFN
        ln_k<<<128, 256, 0, stream>>>(ar + O_X2, ln3_g + i * 512, ln3_b + i * 512, lnx);
        gemm_sk<<<dim3(32, 2, 4), 256, 0, stream>>>(lnx, 512, ffn_w1 + (size_t)i * 1048576, 512,
                                                    ffn_b1 + i * 2048, nullptr, 0,
                                                    ar + O_FFNH, 2048, 0);
        gemm_sk<<<dim3(8, 2, 16), 256, 0, stream>>>(ar + O_FFNH, 2048, ffn_w2 + (size_t)i * 1048576, 2048,
                                                    ffn_b2 + i * 512, lnx, 512,
                                                    ar + O_QNEXT, 512, 1);

        qcur = ar + O_QNEXT;
    }
}